// Round 12
// baseline (13536.002 us; speedup 1.0000x reference)
//
#include <hip/hip_runtime.h>
#include <hip/hip_fp16.h>

#define T_LEN 4096
#define HID   256
#define G4    1024
#define DIRSZ (1024 * 128)   // packed weight u32 per direction

typedef unsigned int u32;
typedef unsigned long long u64;
typedef _Float16 half2_t __attribute__((ext_vector_type(2)));

__device__ __forceinline__ float dot2f(u32 w, u32 h, float acc) {
#if __has_builtin(__builtin_amdgcn_fdot2)
    return __builtin_amdgcn_fdot2(__builtin_bit_cast(half2_t, w),
                                  __builtin_bit_cast(half2_t, h), acc, false);
#else
    __half2 wh = __builtin_bit_cast(__half2, w);
    __half2 hh = __builtin_bit_cast(__half2, h);
    float2 wf = __half22float2(wh), hf = __half22float2(hh);
    return acc + wf.x * hf.x + wf.y * hf.y;
#endif
}

// 8-lane tree-sum: DPP quad_perm xor1 (0xB1), xor2 (0x4E), then ds_swizzle
// xor4 (BitMode offset 0x101F, operates on lane[4:0] - all 8-lane j-groups
// sit inside one 32-lane half, so this is exact).
__device__ __forceinline__ float qsum8(float v) {
    int i = __builtin_bit_cast(int, v);
    v += __builtin_bit_cast(float,
         __builtin_amdgcn_update_dpp(i, i, 0xB1, 0xF, 0xF, true));
    i = __builtin_bit_cast(int, v);
    v += __builtin_bit_cast(float,
         __builtin_amdgcn_update_dpp(i, i, 0x4E, 0xF, 0xF, true));
    i = __builtin_bit_cast(int, v);
    v += __builtin_bit_cast(float, __builtin_amdgcn_ds_swizzle(i, 0x101F));
    return v;
}

__device__ __forceinline__ u32 pack2(float a, float b) {
    unsigned short lo = __half_as_ushort(__float2half(a));
    unsigned short hi = __half_as_ushort(__float2half(b));
    return ((u32)hi << 16) | (u32)lo;
}

// lgkm-only barrier: never drains vmcnt (global stores/loads keep flying)
__device__ __forceinline__ void step_barrier() {
    asm volatile("s_waitcnt lgkmcnt(0)" ::: "memory");
    __builtin_amdgcn_s_barrier();
    __builtin_amdgcn_sched_barrier(0);
}

// ---------------- zero helper (exchange tags must be 0 at each launch) -------
__global__ void k_zero(u32* __restrict__ p, int n) {
    int q = blockIdx.x * 256 + threadIdx.x;
    if (q < n) p[q] = 0u;
}

// ---------------- transpose: out[k*N+n] = in[n*K+k] ----------------
__global__ void k_transpose(const float* __restrict__ in, float* __restrict__ out,
                            int N, int K) {
    int q = blockIdx.x * 256 + threadIdx.x;
    if (q >= N * K) return;
    int n = q / K, k = q % K;
    out[(size_t)k * N + n] = in[q];
}

// ---------------- pack Whh -> 8-way quad layout, PRE-ROTATED -----------------
// Scan thread (slice sl 0..3, tid): j=tid>>3 (unit), q=tid&7 (k-eighth).
// Owns 4 gate-rows of unit 64*sl+j, k-pairs [16q,16q+16).
// regw[g*16 + 4*bb + i] = W[row][pair 16q + 4*((bb+q)&3) + i]  (rotation is
// baked in here so the scan's regw indices stay COMPILE-TIME - rule #20).
__global__ void k_pack_q8(const float* __restrict__ W, u32* __restrict__ out) {
    int idx = blockIdx.x * 256 + threadIdx.x;    // 4*512*64 = 131072 total
    if (idx >= 1024 * 128) return;
    int widx = idx & 63;
    int tid  = (idx >> 6) & 511;
    int sl   = idx >> 15;
    int g = widx >> 4, rem = widx & 15;
    int bb = rem >> 2, i = rem & 3;
    int j = tid >> 3, q = tid & 7;
    int row = g * 256 + 64 * sl + j;
    int pair = 16 * q + 4 * ((bb + q) & 3) + i;
    out[idx] = pack2(W[row * 256 + 2 * pair], W[row * 256 + 2 * pair + 1]);
}

// ---------------- generic GEMM: C[M,N] = A[M,K] @ Wt[K,N] (+bias/relu/cosine)
__global__ __launch_bounds__(256) void k_gemm(
    const float* __restrict__ A, const float* __restrict__ Wt,
    const float* __restrict__ bias, const float* __restrict__ norms,
    float* __restrict__ C, int M, int N, int K, int mode) {
    __shared__ float As[16 * 512];
    const int tid = threadIdx.x;
    const int m0 = blockIdx.x * 16;
    const int n  = blockIdx.y * 256 + tid;

    for (int i = tid; i < 16 * K; i += 256) As[i] = A[(size_t)m0 * K + i];
    __syncthreads();

    float acc[16];
#pragma unroll
    for (int m = 0; m < 16; ++m) acc[m] = 0.f;

#pragma unroll 4
    for (int k = 0; k < K; ++k) {
        float w = Wt[(size_t)k * N + n];
#pragma unroll
        for (int m = 0; m < 16; ++m) acc[m] += As[m * K + k] * w;
    }

    float bn = bias ? bias[n] : 0.f;
#pragma unroll
    for (int m = 0; m < 16; ++m) {
        float v = acc[m] + bn;
        if (mode == 1) v = fmaxf(v, 0.f);
        if (mode == 2) {
            float d = norms[m0 + m] * norms[n];
            v = 1.f - fmaxf(acc[m] / d, 1e-6f);
        }
        C[(size_t)(m0 + m) * N + n] = v;
    }
}

// ---------------- row norms of e (4096 x 256) ----------------
__global__ void k_norms(const float* __restrict__ e, float* __restrict__ norms) {
    int i = blockIdx.x, lane = threadIdx.x;
    float s = 0.f;
    for (int k = lane; k < 256; k += 64) { float v = e[i * 256 + k]; s += v * v; }
    for (int off = 32; off; off >>= 1) s += __shfl_down(s, off);
    if (lane == 0) norms[i] = sqrtf(s);
}

// ---------------- 4-slice-per-direction scan (v11) ----------------
// Grid 8 = 2 dirs x 4 slices: dir=bid&1, s=bid>>1. 512 threads.
// Thread (j=tid>>3, q=tid&7) owns 4 gate-rows of unit U=64s+j, k-eighth
// [16q,16q+16): 64 weight u32, 4 b128 h-reads (address-rotated, <=2-way bank),
// 64 dots, 8-lane qsum8 reduce -> gates in-thread (r10 pattern, halved/CU).
// Exchange: r10's proven protocol extended to 3 partners - 32 u64 tag|payload
// words per slice, relaxed agent stores, relaxed polls, parity double-buffer
// (consume-all-partners-per-step makes overwrite-before-read impossible).
// One lgkm-only barrier per step.
__global__ __launch_bounds__(512, 2) void k_scan_q8(
    const float* __restrict__ xs, const u32* __restrict__ rp,
    u64* __restrict__ ex, float* __restrict__ hout) {
    __shared__ alignas(16) u32 hb[2][128];   // h(t-1)/h(t), f16x2 packed

    const int bid = blockIdx.x;
    const int dir = bid & 1;
    const int s   = bid >> 1;        // slice 0..3
    const int tid = threadIdx.x;
    const int j   = tid >> 3;        // unit within slice, 0..63
    const int q   = tid & 7;         // k-eighth
    const int gq  = q & 3;           // gate row this lane loads xs for
    const int U   = 64 * s + j;      // unit within direction, 0..255

    xs += (size_t)dir * (T_LEN * G4);
    rp += (size_t)dir * DIRSZ;
    u64* exd = ex + dir * 256;       // [parity(2)][slice(4)][word(32)]

    u32 regw[64];
    {
        const uint4* rp4 = (const uint4*)(rp + (size_t)(s * 512 + tid) * 64);
#pragma unroll
        for (int p = 0; p < 16; ++p) {
            uint4 v = rp4[p];
            regw[4 * p + 0] = v.x; regw[4 * p + 1] = v.y;
            regw[4 * p + 2] = v.z; regw[4 * p + 3] = v.w;
        }
    }
    if (tid < 128) { hb[0][tid] = 0u; hb[1][tid] = 0u; }
    float cst = 0.f;
    __syncthreads();

    int tt = dir ? (T_LEN - 1) : 0;
    const int stp = dir ? -1 : 1;
    float xa = xs[(size_t)tt * G4 + (gq * 256 + U)];

    for (int t = 0; t < T_LEN; ++t) {
        const int cur = t & 1, nxt = cur ^ 1;
        int tn = (t + 1 < T_LEN) ? tt + stp : tt;
        float acc0 = (q == 0) ? xa : 0.f;    // i
        float acc1 = (q == 1) ? xa : 0.f;    // f
        float acc2 = (q == 2) ? xa : 0.f;    // g
        float acc3 = (q == 3) ? xa : 0.f;    // o
        xa = xs[(size_t)tn * G4 + (gq * 256 + U)];    // prefetch (never drained)

        // 4 b128 reads over this lane's k-eighth, address-rotated by q;
        // each feeds 4 dots x 4 gate-rows (regw indices compile-time).
        const u32* hq = &hb[cur][16 * q];
#pragma unroll
        for (int bb = 0; bb < 4; ++bb) {
            uint4 hv4 = *(const uint4*)&hq[4 * ((bb + q) & 3)];
            u32 hh[4] = { hv4.x, hv4.y, hv4.z, hv4.w };
#pragma unroll
            for (int i = 0; i < 4; ++i) {
                const int p = 4 * bb + i;            // compile-time index
                acc0 = dot2f(regw[p],       hh[i], acc0);
                acc1 = dot2f(regw[16 + p],  hh[i], acc1);
                acc2 = dot2f(regw[32 + p],  hh[i], acc2);
                acc3 = dot2f(regw[48 + p],  hh[i], acc3);
            }
        }

        // 8-lane tree-sum -> every lane has full z for unit U
        float zi = qsum8(acc0), zf = qsum8(acc1);
        float zg = qsum8(acc2), zo = qsum8(acc3);

        // gates in-thread (redundant x8, no divergence)
        float si = 1.f / (1.f + __expf(-zi));
        float sf = 1.f / (1.f + __expf(-zf));
        float so = 1.f / (1.f + __expf(-zo));
        float tg = 1.f - 2.f / (__expf(2.f * zg) + 1.f);
        cst = sf * cst + si * tg;
        float th = 1.f - 2.f / (__expf(2.f * cst) + 1.f);
        float hv = so * th;

        // neighbor unit's h (j^1, same q): lane tid^8 -> ds_swizzle xor8
        float hn = __builtin_bit_cast(float,
            __builtin_amdgcn_ds_swizzle(__builtin_bit_cast(int, hv), 0x201F));

        if (q == 0)                          // own h -> next LDS buffer (f16)
            ((__half*)hb[nxt])[64 * s + j] = __float2half(hv);
        if (q == 0 && !(j & 1)) {            // publish word (2 units)
            u32 hp = pack2(hv, hn);
            u64 pay = ((u64)(u32)(t + 1) << 32) | (u64)hp;
            __hip_atomic_store(&exd[(cur * 4 + s) * 32 + (j >> 1)], pay,
                               __ATOMIC_RELAXED, __HIP_MEMORY_SCOPE_AGENT);
        }
        if (q == 1)                          // unquantized h -> hout
            hout[(size_t)tt * 512 + dir * 256 + U] = hv;
        if (tid < 96 && (t + 1 < T_LEN)) {   // poll 3 partners (one word each)
            int p_ = tid >> 5, w = tid & 31;
            int ps = (p_ < s) ? p_ : p_ + 1;
            u64 v;
            do {
                v = __hip_atomic_load(&exd[(cur * 4 + ps) * 32 + w],
                                      __ATOMIC_RELAXED, __HIP_MEMORY_SCOPE_AGENT);
            } while ((u32)(v >> 32) != (u32)(t + 1));
            hb[nxt][32 * ps + w] = (u32)v;
        }
        step_barrier();                      // single barrier/step (lgkm only)
        tt = tn;
    }
}

// ---------------- launcher ----------------
extern "C" void kernel_launch(void* const* d_in, const int* in_sizes, int n_in,
                              void* d_out, int out_size, void* d_ws, size_t ws_size,
                              hipStream_t stream) {
    const float* x       = (const float*)d_in[0];
    const float* wih_l0f = (const float*)d_in[1];
    const float* whh_l0f = (const float*)d_in[2];
    const float* b_l0f   = (const float*)d_in[3];
    const float* wih_l0b = (const float*)d_in[4];
    const float* whh_l0b = (const float*)d_in[5];
    const float* b_l0b   = (const float*)d_in[6];
    const float* wih_l1f = (const float*)d_in[7];
    const float* whh_l1f = (const float*)d_in[8];
    const float* b_l1f   = (const float*)d_in[9];
    const float* wih_l1b = (const float*)d_in[10];
    const float* whh_l1b = (const float*)d_in[11];
    const float* b_l1b   = (const float*)d_in[12];
    const float* fc1_w   = (const float*)d_in[13];
    const float* fc1_b   = (const float*)d_in[14];
    const float* fc2_w   = (const float*)d_in[15];
    const float* fc2_b   = (const float*)d_in[16];
    float* outp = (float*)d_out;

    char* ws = (char*)d_ws;
    size_t off = 0;
    auto alloc = [&](size_t nbytes) {
        char* p = ws + off;
        off += (nbytes + 255) & ~(size_t)255;
        return p;
    };
    float* xs0   = (float*)alloc((size_t)2 * T_LEN * G4 * 4);
    float* xs1   = (float*)alloc((size_t)2 * T_LEN * G4 * 4);
    float* h1    = (float*)alloc((size_t)T_LEN * 512 * 4);
    float* h2    = (float*)alloc((size_t)T_LEN * 512 * 4);
    float* zb    = (float*)alloc((size_t)T_LEN * 256 * 4);
    float* eb    = (float*)alloc((size_t)T_LEN * 256 * 4);
    float* etb   = (float*)alloc((size_t)T_LEN * 256 * 4);
    float* nrm   = (float*)alloc((size_t)T_LEN * 4);
    float* wt0f  = (float*)alloc((size_t)128 * 1024 * 4);
    float* wt0b  = (float*)alloc((size_t)128 * 1024 * 4);
    float* wt1f  = (float*)alloc((size_t)512 * 1024 * 4);
    float* wt1b  = (float*)alloc((size_t)512 * 1024 * 4);
    float* wtf1  = (float*)alloc((size_t)512 * 256 * 4);
    float* wtf2  = (float*)alloc((size_t)256 * 256 * 4);
    u32*   rpm0  = (u32*)alloc((size_t)2 * DIRSZ * 4);
    u32*   rpm1  = (u32*)alloc((size_t)2 * DIRSZ * 4);
    u64*   exA   = (u64*)alloc((size_t)512 * 8);   // 2dir x 2par x 4sl x 32
    u64*   exB   = (u64*)alloc((size_t)512 * 8);

    // reset exchange tags (every launch / graph replay); exA,exB contiguous
    k_zero<<<8, 256, 0, stream>>>((u32*)exA, 2048);

    // weight transposes
    k_transpose<<<(1024 * 128 + 255) / 256, 256, 0, stream>>>(wih_l0f, wt0f, 1024, 128);
    k_transpose<<<(1024 * 128 + 255) / 256, 256, 0, stream>>>(wih_l0b, wt0b, 1024, 128);
    k_transpose<<<(1024 * 512 + 255) / 256, 256, 0, stream>>>(wih_l1f, wt1f, 1024, 512);
    k_transpose<<<(1024 * 512 + 255) / 256, 256, 0, stream>>>(wih_l1b, wt1b, 1024, 512);
    k_transpose<<<(256 * 512 + 255) / 256, 256, 0, stream>>>(fc1_w, wtf1, 256, 512);
    k_transpose<<<(256 * 256 + 255) / 256, 256, 0, stream>>>(fc2_w, wtf2, 256, 256);

    // recurrent weight packs (8-way quad layout, pre-rotated)
    k_pack_q8<<<512, 256, 0, stream>>>(whh_l0f, rpm0);
    k_pack_q8<<<512, 256, 0, stream>>>(whh_l0b, rpm0 + DIRSZ);
    k_pack_q8<<<512, 256, 0, stream>>>(whh_l1f, rpm1);
    k_pack_q8<<<512, 256, 0, stream>>>(whh_l1b, rpm1 + DIRSZ);

    dim3 g1024(T_LEN / 16, 4);
    // layer 0 input projections
    k_gemm<<<g1024, 256, 0, stream>>>(x, wt0f, b_l0f, nullptr, xs0, T_LEN, 1024, 128, 0);
    k_gemm<<<g1024, 256, 0, stream>>>(x, wt0b, b_l0b, nullptr, xs0 + (size_t)T_LEN * G4, T_LEN, 1024, 128, 0);
    // layer 0 scan (2 dirs x 4 slices on 8 CUs)
    k_scan_q8<<<8, 512, 0, stream>>>(xs0, rpm0, exA, h1);
    // layer 1 input projections
    k_gemm<<<g1024, 256, 0, stream>>>(h1, wt1f, b_l1f, nullptr, xs1, T_LEN, 1024, 512, 0);
    k_gemm<<<g1024, 256, 0, stream>>>(h1, wt1b, b_l1b, nullptr, xs1 + (size_t)T_LEN * G4, T_LEN, 1024, 512, 0);
    // layer 1 scan
    k_scan_q8<<<8, 512, 0, stream>>>(xs1, rpm1, exB, h2);
    // FC head
    k_gemm<<<dim3(T_LEN / 16, 1), 256, 0, stream>>>(h2, wtf1, fc1_b, nullptr, zb, T_LEN, 256, 512, 1);
    k_gemm<<<dim3(T_LEN / 16, 1), 256, 0, stream>>>(zb, wtf2, fc2_b, nullptr, eb, T_LEN, 256, 256, 0);
    // cosine-similarity output
    k_transpose<<<(T_LEN * 256 + 255) / 256, 256, 0, stream>>>(eb, etb, T_LEN, 256);
    k_norms<<<T_LEN, 64, 0, stream>>>(eb, nrm);
    k_gemm<<<dim3(T_LEN / 16, T_LEN / 256), 256, 0, stream>>>(eb, etb, nullptr, nrm, outp, T_LEN, T_LEN, 256, 2);
}

// Round 13
// 12219.934 us; speedup vs baseline: 1.1077x; 1.1077x over previous
//
#include <hip/hip_runtime.h>
#include <hip/hip_fp16.h>

#define T_LEN 4096
#define HID   256
#define G4    1024
#define DIRSZ (1024 * 128)   // packed weight u32 per direction

typedef unsigned int u32;
typedef unsigned long long u64;
typedef _Float16 half2_t __attribute__((ext_vector_type(2)));

__device__ __forceinline__ float dot2f(u32 w, u32 h, float acc) {
#if __has_builtin(__builtin_amdgcn_fdot2)
    return __builtin_amdgcn_fdot2(__builtin_bit_cast(half2_t, w),
                                  __builtin_bit_cast(half2_t, h), acc, false);
#else
    __half2 wh = __builtin_bit_cast(__half2, w);
    __half2 hh = __builtin_bit_cast(__half2, h);
    float2 wf = __half22float2(wh), hf = __half22float2(hh);
    return acc + wf.x * hf.x + wf.y * hf.y;
#endif
}

// quad (4-lane) tree-sum via DPP quad_perm (pure VALU, no LDS pipe):
// xor1 = quad_perm(1,0,3,2)=0xB1, xor2 = quad_perm(2,3,0,1)=0x4E.
__device__ __forceinline__ float qsum(float v) {
    int i = __builtin_bit_cast(int, v);
    v += __builtin_bit_cast(float,
         __builtin_amdgcn_update_dpp(i, i, 0xB1, 0xF, 0xF, true));
    i = __builtin_bit_cast(int, v);
    v += __builtin_bit_cast(float,
         __builtin_amdgcn_update_dpp(i, i, 0x4E, 0xF, 0xF, true));
    return v;
}

__device__ __forceinline__ u32 pack2(float a, float b) {
    unsigned short lo = __half_as_ushort(__float2half(a));
    unsigned short hi = __half_as_ushort(__float2half(b));
    return ((u32)hi << 16) | (u32)lo;
}

// lgkm-only barrier: never drains vmcnt (global stores/loads keep flying)
__device__ __forceinline__ void step_barrier() {
    asm volatile("s_waitcnt lgkmcnt(0)" ::: "memory");
    __builtin_amdgcn_s_barrier();
    __builtin_amdgcn_sched_barrier(0);
}

// ---------------- zero helper (exchange tags must be 0 at each launch) -------
__global__ void k_zero(u32* __restrict__ p, int n) {
    int q = blockIdx.x * 256 + threadIdx.x;
    if (q < n) p[q] = 0u;
}

// ---------------- transpose: out[k*N+n] = in[n*K+k] ----------------
__global__ void k_transpose(const float* __restrict__ in, float* __restrict__ out,
                            int N, int K) {
    int q = blockIdx.x * 256 + threadIdx.x;
    if (q >= N * K) return;
    int n = q / K, k = q % K;
    out[(size_t)k * N + n] = in[q];
}

// ---------------- pack Whh -> quad layout, own-half-first, PRE-ROTATED -------
// Scan thread (slice sl, tid): j=tid>>2 (unit), q=tid&3 (k-quarter).
// Owns 4 gate-rows of unit U=128*sl+j. regw word widx decodes as
//   g = widx>>5, half = (widx>>4)&1, bb = (widx>>2)&3, i = widx&3
// and equals W[g*256+U][pair], pair = 64*srcsl + 16*q + 4*((bb+q)&3) + i,
// srcsl = half ? 1-sl : sl.  (Rotation baked in; scan regw indices are
// compile-time - rule #20, r9's 90ms lesson.)
__global__ void k_pack_sp(const float* __restrict__ W, u32* __restrict__ out) {
    int idx = blockIdx.x * 256 + threadIdx.x;    // 1024*128 = 131072 total
    if (idx >= 1024 * 128) return;
    int widx = idx & 127;
    int tid  = (idx >> 7) & 511;
    int sl   = idx >> 16;                        // 512*128 = 65536 per slice
    int g = widx >> 5, half = (widx >> 4) & 1;
    int bb = (widx >> 2) & 3, i = widx & 3;
    int j = tid >> 2, q = tid & 3;
    int U = 128 * sl + j;
    int row = g * 256 + U;
    int srcsl = half ? (1 - sl) : sl;
    int pair = 64 * srcsl + 16 * q + 4 * ((bb + q) & 3) + i;
    out[idx] = pack2(W[row * 256 + 2 * pair], W[row * 256 + 2 * pair + 1]);
}

// ---------------- generic GEMM: C[M,N] = A[M,K] @ Wt[K,N] (+bias/relu/cosine)
__global__ __launch_bounds__(256) void k_gemm(
    const float* __restrict__ A, const float* __restrict__ Wt,
    const float* __restrict__ bias, const float* __restrict__ norms,
    float* __restrict__ C, int M, int N, int K, int mode) {
    __shared__ float As[16 * 512];
    const int tid = threadIdx.x;
    const int m0 = blockIdx.x * 16;
    const int n  = blockIdx.y * 256 + tid;

    for (int i = tid; i < 16 * K; i += 256) As[i] = A[(size_t)m0 * K + i];
    __syncthreads();

    float acc[16];
#pragma unroll
    for (int m = 0; m < 16; ++m) acc[m] = 0.f;

#pragma unroll 4
    for (int k = 0; k < K; ++k) {
        float w = Wt[(size_t)k * N + n];
#pragma unroll
        for (int m = 0; m < 16; ++m) acc[m] += As[m * K + k] * w;
    }

    float bn = bias ? bias[n] : 0.f;
#pragma unroll
    for (int m = 0; m < 16; ++m) {
        float v = acc[m] + bn;
        if (mode == 1) v = fmaxf(v, 0.f);
        if (mode == 2) {
            float d = norms[m0 + m] * norms[n];
            v = 1.f - fmaxf(acc[m] / d, 1e-6f);
        }
        C[(size_t)(m0 + m) * N + n] = v;
    }
}

// ---------------- row norms of e (4096 x 256) ----------------
__global__ void k_norms(const float* __restrict__ e, float* __restrict__ norms) {
    int i = blockIdx.x, lane = threadIdx.x;
    float s = 0.f;
    for (int k = lane; k < 256; k += 64) { float v = e[i * 256 + k]; s += v * v; }
    for (int off = 32; off; off >>= 1) s += __shfl_down(s, off);
    if (lane == 0) norms[i] = sqrtf(s);
}

// ---------------- split-k 2-CU-per-direction scan (v13) ----------------
// r10 frame: 16 blocks, workers {0,1,8,9}: dir=bid&7, s=bid>>3; 512 threads;
// thread (j=tid>>2, q=tid&3) owns 4 gate-rows of unit U=128s+j, quad layout,
// 128 weight u32 in regs (own-16-pairs first, remote-16 after).
//
// Exchange-latency hiding (the measured r10/r12 wall, ~1000-1500cy exposed):
//  - loop top: ISSUE the remote poll load (u32 = tag16|h_f16, relaxed agent) -
//    data was published a full iteration ago, so the load overlaps phase 1.
//  - phase 1: own-half dots (local h, no wait).
//  - check tag (rarely spins), LDS-write remote half. [bar]
//  - phase 2: remote-half dots; quad-reduce; gates.
//  - write own h -> LDS(nxt); publish u32 (tag t+1 | f16 h) fire-and-forget.
//    [bar]
// Safety: parity slots + partner needs our tag-(t+1) words to pass its next
// step -> max skew 1 step, overwrite needs 2.
__global__ __launch_bounds__(512, 2) void k_scan_sp(
    const float* __restrict__ xs, const u32* __restrict__ rp,
    u32* __restrict__ ex, float* __restrict__ hout) {
    __shared__ alignas(16) u32 hb[2][128];   // h(t-1)/h(t), f16x2 packed

    const int bid = blockIdx.x;
    if ((bid & 7) > 1 || (bid >> 3) > 1) return;
    const int dir = bid & 7;
    const int s   = bid >> 3;
    const int rs  = 1 - s;
    const int tid = threadIdx.x;
    const int j   = tid >> 2;        // unit within slice, 0..127
    const int q   = tid & 3;         // k-quarter
    const int U   = 128 * s + j;     // unit within direction, 0..255

    xs += (size_t)dir * (T_LEN * G4);
    rp += (size_t)dir * DIRSZ;
    u32* exd = ex + dir * 512;       // [parity(2)][slice(2)][unit(128)] u32

    u32 regw[128];
    {
        const uint4* rp4 = (const uint4*)(rp + (size_t)(s * 512 + tid) * 128);
#pragma unroll
        for (int p = 0; p < 32; ++p) {
            uint4 v = rp4[p];
            regw[4 * p + 0] = v.x; regw[4 * p + 1] = v.y;
            regw[4 * p + 2] = v.z; regw[4 * p + 3] = v.w;
        }
    }
    if (tid < 128) { hb[0][tid] = 0u; hb[1][tid] = 0u; }
    float cst = 0.f;
    __syncthreads();

    int tt = dir ? (T_LEN - 1) : 0;
    const int stp = dir ? -1 : 1;
    float xa = xs[(size_t)tt * G4 + (q * 256 + U)];

    for (int t = 0; t < T_LEN; ++t) {
        const int cur = t & 1, nxt = cur ^ 1;
        int tn = (t + 1 < T_LEN) ? tt + stp : tt;

        // issue-early remote poll load (tag t expected; published last iter)
        u32 pv = 0;
        if (t > 0 && tid < 128)
            pv = __hip_atomic_load(&exd[cur * 256 + rs * 128 + tid],
                                   __ATOMIC_RELAXED, __HIP_MEMORY_SCOPE_AGENT);

        float acc0 = (q == 0) ? xa : 0.f;    // i
        float acc1 = (q == 1) ? xa : 0.f;    // f
        float acc2 = (q == 2) ? xa : 0.f;    // g
        float acc3 = (q == 3) ? xa : 0.f;    // o
        xa = xs[(size_t)tn * G4 + (q * 256 + U)];     // prefetch (never drained)

        // ---- phase 1: own-half dots (4 b128, address-rotated, 64 dots) ----
        const u32* ho = &hb[cur][64 * s + 16 * q];
#pragma unroll
        for (int bb = 0; bb < 4; ++bb) {
            uint4 hv4 = *(const uint4*)&ho[4 * ((bb + q) & 3)];
            u32 hh[4] = { hv4.x, hv4.y, hv4.z, hv4.w };
#pragma unroll
            for (int i = 0; i < 4; ++i) {
                const int p = 4 * bb + i;            // compile-time index
                acc0 = dot2f(regw[p],       hh[i], acc0);
                acc1 = dot2f(regw[32 + p],  hh[i], acc1);
                acc2 = dot2f(regw[64 + p],  hh[i], acc2);
                acc3 = dot2f(regw[96 + p],  hh[i], acc3);
            }
        }

        // check (RTT already overlapped by phase 1) + LDS-write remote half
        if (t > 0 && tid < 128) {
            while ((pv >> 16) != (u32)t)
                pv = __hip_atomic_load(&exd[cur * 256 + rs * 128 + tid],
                                       __ATOMIC_RELAXED, __HIP_MEMORY_SCOPE_AGENT);
            ((__half*)hb[cur])[128 * rs + tid] =
                __ushort_as_half((unsigned short)(pv & 0xffffu));
        }
        step_barrier();

        // ---- phase 2: remote-half dots (regw offset +16) ----
        const u32* hr = &hb[cur][64 * rs + 16 * q];
#pragma unroll
        for (int bb = 0; bb < 4; ++bb) {
            uint4 hv4 = *(const uint4*)&hr[4 * ((bb + q) & 3)];
            u32 hh[4] = { hv4.x, hv4.y, hv4.z, hv4.w };
#pragma unroll
            for (int i = 0; i < 4; ++i) {
                const int p = 16 + 4 * bb + i;       // compile-time index
                acc0 = dot2f(regw[p],       hh[i], acc0);
                acc1 = dot2f(regw[32 + p],  hh[i], acc1);
                acc2 = dot2f(regw[64 + p],  hh[i], acc2);
                acc3 = dot2f(regw[96 + p],  hh[i], acc3);
            }
        }

        // quad tree-sum -> every lane has full z for unit U
        float zi = qsum(acc0), zf = qsum(acc1), zg = qsum(acc2), zo = qsum(acc3);

        // gates in-thread (redundant x4, no divergence)
        float si = 1.f / (1.f + __expf(-zi));
        float sf = 1.f / (1.f + __expf(-zf));
        float so = 1.f / (1.f + __expf(-zo));
        float tg = 1.f - 2.f / (__expf(2.f * zg) + 1.f);
        cst = sf * cst + si * tg;
        float th = 1.f - 2.f / (__expf(2.f * cst) + 1.f);
        float hv = so * th;

        if (q == 0) {
            unsigned short h16 = __half_as_ushort(__float2half(hv));
            ((__half*)hb[nxt])[128 * s + j] = __ushort_as_half(h16);
            // publish into slot[(t+1)&1] with tag t+1 (fire-and-forget)
            __hip_atomic_store(&exd[nxt * 256 + s * 128 + j],
                               ((u32)(t + 1) << 16) | (u32)h16,
                               __ATOMIC_RELAXED, __HIP_MEMORY_SCOPE_AGENT);
        }
        if (q == 1)                          // unquantized h -> hout
            hout[(size_t)tt * 512 + dir * 256 + U] = hv;

        step_barrier();
        tt = tn;
    }
}

// ---------------- launcher ----------------
extern "C" void kernel_launch(void* const* d_in, const int* in_sizes, int n_in,
                              void* d_out, int out_size, void* d_ws, size_t ws_size,
                              hipStream_t stream) {
    const float* x       = (const float*)d_in[0];
    const float* wih_l0f = (const float*)d_in[1];
    const float* whh_l0f = (const float*)d_in[2];
    const float* b_l0f   = (const float*)d_in[3];
    const float* wih_l0b = (const float*)d_in[4];
    const float* whh_l0b = (const float*)d_in[5];
    const float* b_l0b   = (const float*)d_in[6];
    const float* wih_l1f = (const float*)d_in[7];
    const float* whh_l1f = (const float*)d_in[8];
    const float* b_l1f   = (const float*)d_in[9];
    const float* wih_l1b = (const float*)d_in[10];
    const float* whh_l1b = (const float*)d_in[11];
    const float* b_l1b   = (const float*)d_in[12];
    const float* fc1_w   = (const float*)d_in[13];
    const float* fc1_b   = (const float*)d_in[14];
    const float* fc2_w   = (const float*)d_in[15];
    const float* fc2_b   = (const float*)d_in[16];
    float* outp = (float*)d_out;

    char* ws = (char*)d_ws;
    size_t off = 0;
    auto alloc = [&](size_t nbytes) {
        char* p = ws + off;
        off += (nbytes + 255) & ~(size_t)255;
        return p;
    };
    float* xs0   = (float*)alloc((size_t)2 * T_LEN * G4 * 4);
    float* xs1   = (float*)alloc((size_t)2 * T_LEN * G4 * 4);
    float* h1    = (float*)alloc((size_t)T_LEN * 512 * 4);
    float* h2    = (float*)alloc((size_t)T_LEN * 512 * 4);
    float* zb    = (float*)alloc((size_t)T_LEN * 256 * 4);
    float* eb    = (float*)alloc((size_t)T_LEN * 256 * 4);
    float* etb   = (float*)alloc((size_t)T_LEN * 256 * 4);
    float* nrm   = (float*)alloc((size_t)T_LEN * 4);
    float* wt0f  = (float*)alloc((size_t)128 * 1024 * 4);
    float* wt0b  = (float*)alloc((size_t)128 * 1024 * 4);
    float* wt1f  = (float*)alloc((size_t)512 * 1024 * 4);
    float* wt1b  = (float*)alloc((size_t)512 * 1024 * 4);
    float* wtf1  = (float*)alloc((size_t)512 * 256 * 4);
    float* wtf2  = (float*)alloc((size_t)256 * 256 * 4);
    u32*   rpm0  = (u32*)alloc((size_t)2 * DIRSZ * 4);
    u32*   rpm1  = (u32*)alloc((size_t)2 * DIRSZ * 4);
    u32*   exA   = (u32*)alloc((size_t)1024 * 4);  // 2dir x 2par x 2sl x 128
    u32*   exB   = (u32*)alloc((size_t)1024 * 4);

    // reset exchange tags (every launch / graph replay); exA,exB contiguous
    k_zero<<<8, 256, 0, stream>>>(exA, 2048);

    // weight transposes
    k_transpose<<<(1024 * 128 + 255) / 256, 256, 0, stream>>>(wih_l0f, wt0f, 1024, 128);
    k_transpose<<<(1024 * 128 + 255) / 256, 256, 0, stream>>>(wih_l0b, wt0b, 1024, 128);
    k_transpose<<<(1024 * 512 + 255) / 256, 256, 0, stream>>>(wih_l1f, wt1f, 1024, 512);
    k_transpose<<<(1024 * 512 + 255) / 256, 256, 0, stream>>>(wih_l1b, wt1b, 1024, 512);
    k_transpose<<<(256 * 512 + 255) / 256, 256, 0, stream>>>(fc1_w, wtf1, 256, 512);
    k_transpose<<<(256 * 256 + 255) / 256, 256, 0, stream>>>(fc2_w, wtf2, 256, 256);

    // recurrent weight packs (quad layout, own-half-first, pre-rotated)
    k_pack_sp<<<512, 256, 0, stream>>>(whh_l0f, rpm0);
    k_pack_sp<<<512, 256, 0, stream>>>(whh_l0b, rpm0 + DIRSZ);
    k_pack_sp<<<512, 256, 0, stream>>>(whh_l1f, rpm1);
    k_pack_sp<<<512, 256, 0, stream>>>(whh_l1b, rpm1 + DIRSZ);

    dim3 g1024(T_LEN / 16, 4);
    // layer 0 input projections
    k_gemm<<<g1024, 256, 0, stream>>>(x, wt0f, b_l0f, nullptr, xs0, T_LEN, 1024, 128, 0);
    k_gemm<<<g1024, 256, 0, stream>>>(x, wt0b, b_l0b, nullptr, xs0 + (size_t)T_LEN * G4, T_LEN, 1024, 128, 0);
    // layer 0 scan (2 dirs x 2 slices on 4 CUs)
    k_scan_sp<<<16, 512, 0, stream>>>(xs0, rpm0, exA, h1);
    // layer 1 input projections
    k_gemm<<<g1024, 256, 0, stream>>>(h1, wt1f, b_l1f, nullptr, xs1, T_LEN, 1024, 512, 0);
    k_gemm<<<g1024, 256, 0, stream>>>(h1, wt1b, b_l1b, nullptr, xs1 + (size_t)T_LEN * G4, T_LEN, 1024, 512, 0);
    // layer 1 scan
    k_scan_sp<<<16, 512, 0, stream>>>(xs1, rpm1, exB, h2);
    // FC head
    k_gemm<<<dim3(T_LEN / 16, 1), 256, 0, stream>>>(h2, wtf1, fc1_b, nullptr, zb, T_LEN, 256, 512, 1);
    k_gemm<<<dim3(T_LEN / 16, 1), 256, 0, stream>>>(zb, wtf2, fc2_b, nullptr, eb, T_LEN, 256, 256, 0);
    // cosine-similarity output
    k_transpose<<<(T_LEN * 256 + 255) / 256, 256, 0, stream>>>(eb, etb, T_LEN, 256);
    k_norms<<<T_LEN, 64, 0, stream>>>(eb, nrm);
    k_gemm<<<dim3(T_LEN / 16, T_LEN / 256), 256, 0, stream>>>(eb, etb, nullptr, nrm, outp, T_LEN, T_LEN, 256, 2);
}